// Round 1
// baseline (599.766 us; speedup 1.0000x reference)
//
#include <hip/hip_runtime.h>
#include <hip/hip_bf16.h>

// CausalGraphLayer: out = [D^-1/2 (A+I) D^-1/2 (x W) + b] @ softmax(CA)
// Folded: M = W @ softmax(CA); bs = b @ softmax(CA);
//         z[i] = dinv[i] * (x[i] @ M)
//         out[d] = dinv[d] * (z[d] + sum_{(s,d) in E} z[s]) + bs
// N = 100000, E = 1600000, D = 64.

#define D 64

// ---------------- K1: in-degree count ----------------
__global__ __launch_bounds__(256) void deg_kernel(const int* __restrict__ dst,
                                                  int* __restrict__ deg, int E) {
    int t = blockIdx.x * 256 + threadIdx.x;
    if (t < E) atomicAdd(&deg[dst[t]], 1);
}

// ---------------- K2: dinv = rsqrt(deg+1) ----------------
__global__ __launch_bounds__(256) void dinv_kernel(const int* __restrict__ deg,
                                                   float* __restrict__ dinv, int n) {
    int t = blockIdx.x * 256 + threadIdx.x;
    if (t < n) dinv[t] = rsqrtf((float)(deg[t] + 1));
}

// ---------------- K3: S = softmax(A); M = W@S; bs = b@S ----------------
// grid = 16 blocks x 256 threads; block bk computes M rows [bk*4, bk*4+4)
__global__ __launch_bounds__(256) void prep_kernel(const float* __restrict__ W,
                                                   const float* __restrict__ b,
                                                   const float* __restrict__ A,
                                                   float* __restrict__ M,
                                                   float* __restrict__ bs) {
    __shared__ float S[D * D];
    int t = threadIdx.x;
    if (t < D) {
        // softmax of row t of A
        float mx = -1e30f;
        for (int j = 0; j < D; j++) mx = fmaxf(mx, A[t * D + j]);
        float sum = 0.f;
        for (int j = 0; j < D; j++) {
            float v = __expf(A[t * D + j] - mx);
            S[t * D + j] = v;
            sum += v;
        }
        float inv = 1.f / sum;
        for (int j = 0; j < D; j++) S[t * D + j] *= inv;
    }
    __syncthreads();
    int k = blockIdx.x * 4 + (t >> 6);  // M row
    int j = t & 63;                     // M col
    float acc = 0.f;
    for (int d = 0; d < D; d++) acc += W[k * D + d] * S[d * D + j];
    M[k * D + j] = acc;
    if (blockIdx.x == 0 && t < D) {
        float a2 = 0.f;
        for (int d = 0; d < D; d++) a2 += b[d] * S[d * D + t];
        bs[t] = a2;
    }
}

// ---------------- K4: exclusive scan of deg -> rowstart, cursor ----------------
// single block, 1024 threads
__global__ __launch_bounds__(1024) void scan_kernel(const int* __restrict__ deg,
                                                    int* __restrict__ rowstart,
                                                    int* __restrict__ cursor, int n) {
    const int T = 1024;
    int t = threadIdx.x;
    int chunk = (n + T - 1) / T;
    int begin = t * chunk;
    int finish = min(begin + chunk, n);
    int sum = 0;
    for (int i = begin; i < finish; i++) sum += deg[i];
    __shared__ int ssum[T];
    ssum[t] = sum;
    __syncthreads();
    // inclusive Hillis-Steele scan
    for (int off = 1; off < T; off <<= 1) {
        int v = 0;
        if (t >= off) v = ssum[t - off];
        __syncthreads();
        ssum[t] += v;
        __syncthreads();
    }
    int running = ssum[t] - sum;  // exclusive prefix for this thread's chunk
    for (int i = begin; i < finish; i++) {
        rowstart[i] = running;
        cursor[i] = running;
        running += deg[i];
    }
    if (t == T - 1) rowstart[n] = ssum[T - 1];
}

// ---------------- K5: fill CSR ----------------
__global__ __launch_bounds__(256) void fill_kernel(const int* __restrict__ src,
                                                   const int* __restrict__ dst,
                                                   int* __restrict__ cursor,
                                                   int* __restrict__ csr, int E) {
    int t = blockIdx.x * 256 + threadIdx.x;
    if (t < E) {
        int p = atomicAdd(&cursor[dst[t]], 1);
        csr[p] = src[t];
    }
}

// ---------------- K6: z = dinv * (x @ M) ----------------
// block 256 = 16 rows x 16 col-groups(4 cols each); M staged in LDS
__global__ __launch_bounds__(256) void zmat_kernel(const float* __restrict__ x,
                                                   const float* __restrict__ M,
                                                   const float* __restrict__ dinv,
                                                   float* __restrict__ z, int n) {
    __shared__ float Ms[D * D];
    __shared__ float xs[16][D + 1];  // +1 pad: kill 4-way bank alias on broadcast col
    int t = threadIdx.x;
    for (int i = t; i < (D * D) / 4; i += 256)
        ((float4*)Ms)[i] = ((const float4*)M)[i];
    int row0 = blockIdx.x * 16;
    for (int i = t; i < 16 * D; i += 256) {
        int r = i >> 6, c = i & 63;
        xs[r][c] = (row0 + r < n) ? x[(size_t)(row0 + r) * D + c] : 0.f;
    }
    __syncthreads();
    int r = t >> 4;
    int jg = (t & 15) << 2;
    float4 acc = {0.f, 0.f, 0.f, 0.f};
#pragma unroll
    for (int k = 0; k < D; k++) {
        float xv = xs[r][k];
        float4 m = *(const float4*)&Ms[k * D + jg];
        acc.x += xv * m.x;
        acc.y += xv * m.y;
        acc.z += xv * m.z;
        acc.w += xv * m.w;
    }
    int row = row0 + r;
    if (row < n) {
        float di = dinv[row];
        float4 res = {di * acc.x, di * acc.y, di * acc.z, di * acc.w};
        *(float4*)&z[(size_t)row * D + jg] = res;
    }
}

// ---------------- K7: gather-sum over in-edges ----------------
// one wave per node; lane = feature dim
__global__ __launch_bounds__(256) void gather_kernel(const float* __restrict__ z,
                                                     const int* __restrict__ csr,
                                                     const int* __restrict__ rowstart,
                                                     const float* __restrict__ dinv,
                                                     const float* __restrict__ bs,
                                                     float* __restrict__ out, int n) {
    int node = blockIdx.x * 4 + (threadIdx.x >> 6);
    if (node >= n) return;
    int lane = threadIdx.x & 63;
    int start = rowstart[node];
    int end = rowstart[node + 1];
    float acc0 = z[(size_t)node * D + lane];  // self loop term
    float acc1 = 0.f;
    int e = start;
    while (e < end) {
        int cnt = min(end - e, 64);
        int sreg = (lane < cnt) ? csr[e + lane] : 0;
        int k = 0;
        for (; k + 1 < cnt; k += 2) {
            int s0 = __shfl(sreg, k);
            int s1 = __shfl(sreg, k + 1);
            acc0 += z[(size_t)s0 * D + lane];
            acc1 += z[(size_t)s1 * D + lane];
        }
        if (k < cnt) {
            int s0 = __shfl(sreg, k);
            acc0 += z[(size_t)s0 * D + lane];
        }
        e += cnt;
    }
    out[(size_t)node * D + lane] = dinv[node] * (acc0 + acc1) + bs[lane];
}

extern "C" void kernel_launch(void* const* d_in, const int* in_sizes, int n_in,
                              void* d_out, int out_size, void* d_ws, size_t ws_size,
                              hipStream_t stream) {
    const float* x = (const float*)d_in[0];
    const int* ei = (const int*)d_in[1];
    const float* W = (const float*)d_in[2];
    const float* b = (const float*)d_in[3];
    const float* A = (const float*)d_in[4];
    // d_in[5] = L (unused by reference math)

    const int N = in_sizes[0] / D;
    const int E = in_sizes[1] / 2;
    const int* src = ei;
    const int* dst = ei + E;

    // workspace layout (256B aligned)
    char* ws = (char*)d_ws;
    size_t off = 0;
    auto alloc = [&](size_t bytes) -> char* {
        char* p = ws + off;
        off = (off + bytes + 255) & ~(size_t)255;
        return p;
    };
    int* deg = (int*)alloc((size_t)N * 4);
    int* rowstart = (int*)alloc((size_t)(N + 1) * 4);
    int* cursor = (int*)alloc((size_t)N * 4);
    float* dinv = (float*)alloc((size_t)N * 4);
    float* M = (float*)alloc((size_t)D * D * 4);
    float* bs = (float*)alloc((size_t)D * 4);
    int* csr = (int*)alloc((size_t)E * 4);
    float* z = (float*)alloc((size_t)N * D * 4);
    (void)ws_size;

    hipMemsetAsync(deg, 0, (size_t)N * 4, stream);
    deg_kernel<<<(E + 255) / 256, 256, 0, stream>>>(dst, deg, E);
    dinv_kernel<<<(N + 255) / 256, 256, 0, stream>>>(deg, dinv, N);
    prep_kernel<<<16, 256, 0, stream>>>(W, b, A, M, bs);
    scan_kernel<<<1, 1024, 0, stream>>>(deg, rowstart, cursor, N);
    fill_kernel<<<(E + 255) / 256, 256, 0, stream>>>(src, dst, cursor, csr, E);
    zmat_kernel<<<(N + 15) / 16, 256, 0, stream>>>(x, M, dinv, z, N);
    gather_kernel<<<(N + 3) / 4, 256, 0, stream>>>(z, csr, rowstart, dinv, bs, out_size ? (float*)d_out : (float*)d_out, N);
}

// Round 2
// 391.611 us; speedup vs baseline: 1.5315x; 1.5315x over previous
//
#include <hip/hip_runtime.h>
#include <hip/hip_bf16.h>

// CausalGraphLayer: out = [D^-1/2 (A+I) D^-1/2 (x W) + b] @ softmax(CA)
// Folded: M = W @ softmax(CA); bs = b @ softmax(CA);
//         z[i] = dinv[i] * (x[i] @ M)
//         out[d] = dinv[d] * (z[d] + sum_{(s,d) in E} z[s]) + bs
// N = 100000, E = 1600000, D = 64.

#define D 64
#define SCAN_CHUNK 1024  // deg elements per scan block (256 thr x int4)

// ---------------- K1: in-degree count ----------------
__global__ __launch_bounds__(256) void deg_kernel(const int* __restrict__ dst,
                                                  int* __restrict__ deg, int E) {
    int t = blockIdx.x * 256 + threadIdx.x;
    if (t < E) atomicAdd(&deg[dst[t]], 1);
}

// ---------------- K2: dinv = rsqrt(deg+1) ----------------
__global__ __launch_bounds__(256) void dinv_kernel(const int* __restrict__ deg,
                                                   float* __restrict__ dinv, int n) {
    int t = blockIdx.x * 256 + threadIdx.x;
    if (t < n) dinv[t] = rsqrtf((float)(deg[t] + 1));
}

// ---------------- K3: S = softmax(A); M = W@S; bs = b@S ----------------
__global__ __launch_bounds__(256) void prep_kernel(const float* __restrict__ W,
                                                   const float* __restrict__ b,
                                                   const float* __restrict__ A,
                                                   float* __restrict__ M,
                                                   float* __restrict__ bs) {
    __shared__ float S[D * D];
    int t = threadIdx.x;
    if (t < D) {
        float mx = -1e30f;
        for (int j = 0; j < D; j++) mx = fmaxf(mx, A[t * D + j]);
        float sum = 0.f;
        for (int j = 0; j < D; j++) {
            float v = __expf(A[t * D + j] - mx);
            S[t * D + j] = v;
            sum += v;
        }
        float inv = 1.f / sum;
        for (int j = 0; j < D; j++) S[t * D + j] *= inv;
    }
    __syncthreads();
    int k = blockIdx.x * 4 + (t >> 6);  // M row
    int j = t & 63;                     // M col
    float acc = 0.f;
    for (int d = 0; d < D; d++) acc += W[k * D + d] * S[d * D + j];
    M[k * D + j] = acc;
    if (blockIdx.x == 0 && t < D) {
        float a2 = 0.f;
        for (int d = 0; d < D; d++) a2 += b[d] * S[d * D + t];
        bs[t] = a2;
    }
}

// ---------------- hierarchical scan ----------------
// block-level exclusive scan helper (256 threads, Hillis-Steele in LDS)
__device__ __forceinline__ int block_scan_excl256(int val, int* lds) {
    int t = threadIdx.x;
    lds[t] = val;
    __syncthreads();
    for (int off = 1; off < 256; off <<= 1) {
        int v = (t >= off) ? lds[t - off] : 0;
        __syncthreads();
        lds[t] += v;
        __syncthreads();
    }
    return lds[t] - val;  // exclusive prefix
}

// K4a: per-block sums of deg over SCAN_CHUNK-element chunks
__global__ __launch_bounds__(256) void partsum_kernel(const int* __restrict__ deg,
                                                      int* __restrict__ blocksum, int n) {
    __shared__ int lds[256];
    int t = threadIdx.x;
    int base = blockIdx.x * SCAN_CHUNK + t * 4;
    int s = 0;
    if (base + 3 < n) {
        int4 v = *(const int4*)&deg[base];
        s = v.x + v.y + v.z + v.w;
    } else {
        for (int i = 0; i < 4; i++)
            if (base + i < n) s += deg[base + i];
    }
    lds[t] = s;
    __syncthreads();
    for (int off = 128; off > 0; off >>= 1) {
        if (t < off) lds[t] += lds[t + off];
        __syncthreads();
    }
    if (t == 0) blocksum[blockIdx.x] = lds[0];
}

// K4b: single tiny block scans nb block sums (nb <= 1024); writes rowstart[n]=total
__global__ __launch_bounds__(1024) void scanblk_kernel(int* __restrict__ blocksum,
                                                       int* __restrict__ blockoff,
                                                       int* __restrict__ rowstart,
                                                       int nb, int n) {
    __shared__ int lds[1024];
    int t = threadIdx.x;
    int v = (t < nb) ? blocksum[t] : 0;
    lds[t] = v;
    __syncthreads();
    for (int off = 1; off < 1024; off <<= 1) {
        int u = (t >= off) ? lds[t - off] : 0;
        __syncthreads();
        lds[t] += u;
        __syncthreads();
    }
    if (t < nb) blockoff[t] = lds[t] - v;  // exclusive
    if (t == 1023) rowstart[n] = lds[1023];
}

// K4c: final scan — re-scan chunk, add block offset, write rowstart + cursor
__global__ __launch_bounds__(256) void scanout_kernel(const int* __restrict__ deg,
                                                      const int* __restrict__ blockoff,
                                                      int* __restrict__ rowstart,
                                                      int* __restrict__ cursor, int n) {
    __shared__ int lds[256];
    int t = threadIdx.x;
    int base = blockIdx.x * SCAN_CHUNK + t * 4;
    int4 v = {0, 0, 0, 0};
    if (base + 3 < n) {
        v = *(const int4*)&deg[base];
    } else {
        if (base + 0 < n) v.x = deg[base + 0];
        if (base + 1 < n) v.y = deg[base + 1];
        if (base + 2 < n) v.z = deg[base + 2];
        if (base + 3 < n) v.w = deg[base + 3];
    }
    int tsum = v.x + v.y + v.z + v.w;
    int pre = block_scan_excl256(tsum, lds) + blockoff[blockIdx.x];
    int4 rs;
    rs.x = pre;
    rs.y = rs.x + v.x;
    rs.z = rs.y + v.y;
    rs.w = rs.z + v.z;
    if (base + 3 < n) {
        *(int4*)&rowstart[base] = rs;
        *(int4*)&cursor[base] = rs;
    } else {
        if (base + 0 < n) { rowstart[base + 0] = rs.x; cursor[base + 0] = rs.x; }
        if (base + 1 < n) { rowstart[base + 1] = rs.y; cursor[base + 1] = rs.y; }
        if (base + 2 < n) { rowstart[base + 2] = rs.z; cursor[base + 2] = rs.z; }
        if (base + 3 < n) { rowstart[base + 3] = rs.w; cursor[base + 3] = rs.w; }
    }
}

// ---------------- K5: fill CSR ----------------
__global__ __launch_bounds__(256) void fill_kernel(const int* __restrict__ src,
                                                   const int* __restrict__ dst,
                                                   int* __restrict__ cursor,
                                                   int* __restrict__ csr, int E) {
    int t = blockIdx.x * 256 + threadIdx.x;
    if (t < E) {
        int p = atomicAdd(&cursor[dst[t]], 1);
        csr[p] = src[t];
    }
}

// ---------------- K6: z = dinv * (x @ M) ----------------
__global__ __launch_bounds__(256) void zmat_kernel(const float* __restrict__ x,
                                                   const float* __restrict__ M,
                                                   const float* __restrict__ dinv,
                                                   float* __restrict__ z, int n) {
    __shared__ float Ms[D * D];
    __shared__ float xs[16][D + 1];
    int t = threadIdx.x;
    for (int i = t; i < (D * D) / 4; i += 256)
        ((float4*)Ms)[i] = ((const float4*)M)[i];
    int row0 = blockIdx.x * 16;
    for (int i = t; i < 16 * D; i += 256) {
        int r = i >> 6, c = i & 63;
        xs[r][c] = (row0 + r < n) ? x[(size_t)(row0 + r) * D + c] : 0.f;
    }
    __syncthreads();
    int r = t >> 4;
    int jg = (t & 15) << 2;
    float4 acc = {0.f, 0.f, 0.f, 0.f};
#pragma unroll
    for (int k = 0; k < D; k++) {
        float xv = xs[r][k];
        float4 m = *(const float4*)&Ms[k * D + jg];
        acc.x += xv * m.x;
        acc.y += xv * m.y;
        acc.z += xv * m.z;
        acc.w += xv * m.w;
    }
    int row = row0 + r;
    if (row < n) {
        float di = dinv[row];
        float4 res = {di * acc.x, di * acc.y, di * acc.z, di * acc.w};
        *(float4*)&z[(size_t)row * D + jg] = res;
    }
}

// ---------------- K7: gather-sum over in-edges ----------------
__global__ __launch_bounds__(256) void gather_kernel(const float* __restrict__ z,
                                                     const int* __restrict__ csr,
                                                     const int* __restrict__ rowstart,
                                                     const float* __restrict__ dinv,
                                                     const float* __restrict__ bs,
                                                     float* __restrict__ out, int n) {
    int node = blockIdx.x * 4 + (threadIdx.x >> 6);
    if (node >= n) return;
    int lane = threadIdx.x & 63;
    int start = rowstart[node];
    int end = rowstart[node + 1];
    float acc0 = z[(size_t)node * D + lane];  // self loop term
    float acc1 = 0.f;
    int e = start;
    while (e < end) {
        int cnt = min(end - e, 64);
        int sreg = (lane < cnt) ? csr[e + lane] : 0;
        int k = 0;
        for (; k + 1 < cnt; k += 2) {
            int s0 = __shfl(sreg, k);
            int s1 = __shfl(sreg, k + 1);
            acc0 += z[(size_t)s0 * D + lane];
            acc1 += z[(size_t)s1 * D + lane];
        }
        if (k < cnt) {
            int s0 = __shfl(sreg, k);
            acc0 += z[(size_t)s0 * D + lane];
        }
        e += cnt;
    }
    out[(size_t)node * D + lane] = dinv[node] * (acc0 + acc1) + bs[lane];
}

extern "C" void kernel_launch(void* const* d_in, const int* in_sizes, int n_in,
                              void* d_out, int out_size, void* d_ws, size_t ws_size,
                              hipStream_t stream) {
    const float* x = (const float*)d_in[0];
    const int* ei = (const int*)d_in[1];
    const float* W = (const float*)d_in[2];
    const float* b = (const float*)d_in[3];
    const float* A = (const float*)d_in[4];

    const int N = in_sizes[0] / D;
    const int E = in_sizes[1] / 2;
    const int* src = ei;
    const int* dst = ei + E;
    const int NB = (N + SCAN_CHUNK - 1) / SCAN_CHUNK;  // 98 for N=100k (must be <=1024)

    char* ws = (char*)d_ws;
    size_t off = 0;
    auto alloc = [&](size_t bytes) -> char* {
        char* p = ws + off;
        off = (off + bytes + 255) & ~(size_t)255;
        return p;
    };
    int* deg = (int*)alloc((size_t)N * 4);
    int* rowstart = (int*)alloc((size_t)(N + 1) * 4);
    int* cursor = (int*)alloc((size_t)N * 4);
    float* dinv = (float*)alloc((size_t)N * 4);
    float* M = (float*)alloc((size_t)D * D * 4);
    float* bs = (float*)alloc((size_t)D * 4);
    int* csr = (int*)alloc((size_t)E * 4);
    float* z = (float*)alloc((size_t)N * D * 4);
    int* blocksum = (int*)alloc((size_t)NB * 4);
    int* blockoff = (int*)alloc((size_t)NB * 4);
    (void)ws_size;

    hipMemsetAsync(deg, 0, (size_t)N * 4, stream);
    deg_kernel<<<(E + 255) / 256, 256, 0, stream>>>(dst, deg, E);
    dinv_kernel<<<(N + 255) / 256, 256, 0, stream>>>(deg, dinv, N);
    prep_kernel<<<16, 256, 0, stream>>>(W, b, A, M, bs);
    partsum_kernel<<<NB, 256, 0, stream>>>(deg, blocksum, N);
    scanblk_kernel<<<1, 1024, 0, stream>>>(blocksum, blockoff, rowstart, NB, N);
    scanout_kernel<<<NB, 256, 0, stream>>>(deg, blockoff, rowstart, cursor, N);
    fill_kernel<<<(E + 255) / 256, 256, 0, stream>>>(src, dst, cursor, csr, E);
    zmat_kernel<<<(N + 15) / 16, 256, 0, stream>>>(x, M, dinv, z, N);
    gather_kernel<<<(N + 3) / 4, 256, 0, stream>>>(z, csr, rowstart, dinv, bs, (float*)d_out, N);
}